// Round 8
// baseline (117.650 us; speedup 1.0000x reference)
//
#include <hip/hip_runtime.h>

#define TILE 16
#define RR 8
#define ND 17          // 2r+1 displacements per axis
#define HH 512
#define WW 512
#define CC 3
#define BB 4
#define WROWS 32       // window rows/cols in LDS
#define WSTR 44        // window LDS row stride: <=2 distinct addrs/bank per
                       // 16-lane b128 phase (2-way is free, m136); 36 gave 3-way
#define BLK 256        // 4 waves; wave w covers dy = w, w+4, w+8, w+12 (+16 for w0)

typedef float f4a __attribute__((ext_vector_type(4), aligned(4)));
typedef unsigned long long u64;

// x += lane(l+N) within 16-lane DPP row (row_shl:N, VALU pipe, 0 shifted in).
template <int N>
__device__ __forceinline__ float shl_add(float x) {
    return x + __int_as_float(
        __builtin_amdgcn_update_dpp(0, __float_as_int(x), 0x100 + N, 0xF, 0xF, true));
}
// x + lane(x ^ MASK) via ds_swizzle (LDS pipe, MASK < 32)
template <int MASK>
__device__ __forceinline__ float swz_add(float x) {
    int y = __builtin_amdgcn_ds_swizzle(__float_as_int(x), (MASK << 10) | 0x1F);
    return x + __int_as_float(y);
}

// one dy-pass: SAD over the LDS window, reduce (R2-exact order), argmin -> key.
// Valid in lane 0.
__device__ __forceinline__ u64 sad_pass(const float* Wl, const float S[CC][8],
                                        int dy, int i, int h, int jg) {
    float acc[9];
    #pragma unroll
    for (int a = 0; a < 9; ++a) acc[a] = 0.f;
    #pragma unroll
    for (int c = 0; c < CC; ++c) {
        const int wb = c * (WROWS * WSTR) + (dy + i) * WSTR + 8 * (h + jg);
        f4a a0 = *(const f4a*)&Wl[wb + 0];
        f4a a1 = *(const f4a*)&Wl[wb + 4];
        f4a a2 = *(const f4a*)&Wl[wb + 8];
        f4a a3 = *(const f4a*)&Wl[wb + 12];
        float W16[16] = { a0.x, a0.y, a0.z, a0.w, a1.x, a1.y, a1.z, a1.w,
                          a2.x, a2.y, a2.z, a2.w, a3.x, a3.y, a3.z, a3.w };
        #pragma unroll
        for (int a = 0; a < 9; ++a) {
            float s0 = acc[a];
            #pragma unroll
            for (int jl = 0; jl < 8; ++jl)
                s0 += fabsf(W16[a + jl] - S[c][jl]);
            acc[a] = s0;
        }
    }
    // reduce over lane bits 1..5 (jg, i); bit0 (h) preserved.
    // bits 1-3 on VALU (DPP row_shl), xor16/xor32 on LDS pipe (R2-exact).
    #pragma unroll
    for (int a = 0; a < 9; ++a) {
        float x = acc[a];
        x = shl_add<2>(x);        // + lane+2   (bit1)
        x = shl_add<4>(x);        // + lanes+4,+6 (bit2)
        x = shl_add<8>(x);        // + lanes+8..+14 (bit3)
        x = swz_add<16>(x);       // xor16 (bit4)
        x += __shfl_xor(x, 32);   // xor32 (bit5)
        acc[a] = x;
    }
    // per-lane argmin over this h-group's dx (h=1 skips a=0: dx=8 dup);
    // ascending a + strict < keeps the smallest dx on ties.
    float bc = h ? acc[1] : acc[0];
    int   ba = h;
    #pragma unroll
    for (int a = 1; a < 9; ++a)
        if (a > h && acc[a] < bc) { bc = acc[a]; ba = a; }
    const unsigned d = (unsigned)(dy * ND + 8 * h + ba);
    u64 key = ((u64)__float_as_uint(bc) << 32) | d;   // cost>=0: bit order = numeric
    u64 ok  = __shfl_xor(key, 1);                     // other h half
    return ok < key ? ok : key;                       // valid in lane 0
}

__global__ __launch_bounds__(BLK, 8) void tile_kernel(const float* __restrict__ src,
                                                      const float* __restrict__ dst,
                                                      const int* __restrict__ offset,
                                                      float* __restrict__ out) {
    __shared__ float Wl[CC * WROWS * WSTR];   // 16896 B (no Sl: S is in regs)
    __shared__ u64   keyL[4];

    const int bid  = blockIdx.x;
    const int tile = ((bid & 7) << 9) | (bid >> 3);  // XCD-banding swizzle
    const int b  = tile >> 10;
    const int th = (tile >> 5) & 31;
    const int tw = tile & 31;
    const int ti = th * TILE, tj = tw * TILE;
    const int oy = offset[(b * 2 + 0) * 1024 + th * 32 + tw];
    const int ox = offset[(b * 2 + 1) * 1024 + th * 32 + tw];
    const int t  = threadIdx.x;

    // lane map: h=bit0 (dx 0..8 / 8..16), jg=bit1 (j half), i=bits2..5 (row)
    const int wv = t >> 6;
    const int l  = t & 63;
    const int h  = l & 1;
    const int jg = (l >> 1) & 1;
    const int i  = l >> 2;

    // ---- stage 3x32x32 dst window (zero-padded) coalesced into LDS ----
    const int gy0 = ti + oy - RR;
    const int gx0 = tj + ox - RR;
    for (int k = t; k < CC * WROWS * 8; k += BLK) {   // 768 float4 chunks, 3 iters
        int c   = k >> 8;
        int rem = k & 255;
        int row = rem >> 3;
        int cc  = (rem & 7) << 2;
        int gy = gy0 + row;
        int gx = gx0 + cc;
        float4 v = make_float4(0.f, 0.f, 0.f, 0.f);
        if ((unsigned)gy < HH) {
            const float* p = dst + ((size_t)(b * CC + c) * HH + gy) * WW;
            if ((unsigned)gx <= WW - 4) {
                f4a u = *(const f4a*)(p + gx);
                v = make_float4(u.x, u.y, u.z, u.w);
            } else {
                float* ve = (float*)&v;
                #pragma unroll
                for (int e = 0; e < 4; ++e) {
                    int g = gx + e;
                    if ((unsigned)g < WW) ve[e] = p[g];
                }
            }
        }
        *(f4a*)&Wl[c * (WROWS * WSTR) + row * WSTR + cc] = *(f4a*)&v;
    }

    // ---- S fragment straight from global into regs (always in-bounds,
    //      16B-aligned; validated bit-exact in R5/R6) — overlaps Wl staging ----
    float S[CC][8];
    {
        const float* sp = src + ((size_t)(b * CC) * HH + ti + i) * WW + tj + 8 * jg;
        #pragma unroll
        for (int c = 0; c < CC; ++c) {
            f4a s0 = *(const f4a*)(sp + (size_t)c * HH * WW);
            f4a s1 = *(const f4a*)(sp + (size_t)c * HH * WW + 4);
            S[c][0]=s0.x; S[c][1]=s0.y; S[c][2]=s0.z; S[c][3]=s0.w;
            S[c][4]=s1.x; S[c][5]=s1.y; S[c][6]=s1.z; S[c][7]=s1.w;
        }
    }
    __syncthreads();

    // wave wv covers dy = wv, wv+4, wv+8, wv+12 (all < 16), wave 0 also dy=16
    u64 bestkey = sad_pass(Wl, S, wv, i, h, jg);
    #pragma unroll
    for (int p = 1; p < 4; ++p) {
        u64 k2 = sad_pass(Wl, S, wv + 4 * p, i, h, jg);
        if (k2 < bestkey) bestkey = k2;
    }
    if (wv == 0) {
        u64 k2 = sad_pass(Wl, S, 16, i, h, jg);
        if (k2 < bestkey) bestkey = k2;
    }
    if (l == 0) keyL[wv] = bestkey;
    __syncthreads();

    // block-wide winner (u64 min; d in low bits gives exact smallest-d ties)
    u64 wk = keyL[0];
    #pragma unroll
    for (int w = 1; w < 4; ++w) { u64 kw = keyL[w]; if (kw < wk) wk = kw; }
    const int d   = (int)(wk & 0xFFFFFFFFu);
    const int bdy = d / ND;
    const int bdx = d - bdy * ND;

    if (t == 0) out[(b * 2 + 0) * 1024 + th * 32 + tw] = (float)(oy + bdy - RR);
    if (t == 1) out[(b * 2 + 1) * 1024 + th * 32 + tw] = (float)(ox + bdx - RR);

    // aligned tile is already in the LDS window; dwordx4 coalesced stores
    float* aligned = out + BB * 2 * 1024;
    if (t < 192) {
        const int c   = t >> 6;
        const int rem = t & 63;
        const int ii  = rem >> 2;
        const int jj4 = (rem & 3) << 2;
        const float* wp = &Wl[c * (WROWS * WSTR) + (bdy + ii) * WSTR + bdx + jj4];
        float4 v = make_float4(wp[0], wp[1], wp[2], wp[3]);
        *(f4a*)&aligned[((size_t)(b * CC + c) * HH + ti + ii) * WW + tj + jj4] =
            *(f4a*)&v;
    }
}

extern "C" void kernel_launch(void* const* d_in, const int* in_sizes, int n_in,
                              void* d_out, int out_size, void* d_ws, size_t ws_size,
                              hipStream_t stream) {
    const float* src    = (const float*)d_in[0];
    const float* dst    = (const float*)d_in[1];
    const int*   offset = (const int*)d_in[2];
    float*       out    = (float*)d_out;
    tile_kernel<<<dim3(BB * 1024), BLK, 0, stream>>>(src, dst, offset, out);
}

// Round 9
// 113.983 us; speedup vs baseline: 1.0322x; 1.0322x over previous
//
#include <hip/hip_runtime.h>

#define TILE 16
#define RR 8
#define ND 17          // 2r+1 displacements per axis
#define HH 512
#define WW 512
#define CC 3
#define BB 4
#define WROWS 32       // window rows/cols in LDS
#define WSTR 36        // window LDS row stride (R8: 44 vs 36 = identical conflicts)
#define BLK 256        // 4 waves; wave w covers dy = w, w+4, w+8, w+12 (+16 for w0)

typedef float f4a __attribute__((ext_vector_type(4), aligned(4)));
typedef unsigned long long u64;

// x += lane(l+N) within 16-lane DPP row (row_shl:N, VALU pipe, 0 shifted in).
template <int N>
__device__ __forceinline__ float shl_add(float x) {
    return x + __int_as_float(
        __builtin_amdgcn_update_dpp(0, __float_as_int(x), 0x100 + N, 0xF, 0xF, true));
}
// x + lane(x ^ MASK) via ds_swizzle (LDS pipe, MASK < 32)
template <int MASK>
__device__ __forceinline__ float swz_add(float x) {
    int y = __builtin_amdgcn_ds_swizzle(__float_as_int(x), (MASK << 10) | 0x1F);
    return x + __int_as_float(y);
}

// accumulate one channel-chunk (16 W floats vs 8 S floats) into acc — same
// FP order as R8's inner loops
__device__ __forceinline__ void sad_c(const f4a (&w)[4], const float Sc[8],
                                      float (&acc)[9]) {
    float W16[16] = { w[0].x, w[0].y, w[0].z, w[0].w,
                      w[1].x, w[1].y, w[1].z, w[1].w,
                      w[2].x, w[2].y, w[2].z, w[2].w,
                      w[3].x, w[3].y, w[3].z, w[3].w };
    #pragma unroll
    for (int a = 0; a < 9; ++a) {
        float s0 = acc[a];
        #pragma unroll
        for (int jl = 0; jl < 8; ++jl)
            s0 += fabsf(W16[a + jl] - Sc[jl]);
        acc[a] = s0;
    }
}

// R2-exact reduce (bits1-3 DPP, xor16/xor32 LDS) + argmin + lane^1 key min.
// Valid in lane 0.
__device__ __forceinline__ u64 reduce_tail(float (&acc)[9], int dy, int h) {
    #pragma unroll
    for (int a = 0; a < 9; ++a) {
        float x = acc[a];
        x = shl_add<2>(x);        // + lane+2   (bit1)
        x = shl_add<4>(x);        // + lanes+4,+6 (bit2)
        x = shl_add<8>(x);        // + lanes+8..+14 (bit3)
        x = swz_add<16>(x);       // xor16 (bit4)
        x += __shfl_xor(x, 32);   // xor32 (bit5)
        acc[a] = x;
    }
    float bc = h ? acc[1] : acc[0];
    int   ba = h;
    #pragma unroll
    for (int a = 1; a < 9; ++a)
        if (a > h && acc[a] < bc) { bc = acc[a]; ba = a; }
    const unsigned d = (unsigned)(dy * ND + 8 * h + ba);
    u64 key = ((u64)__float_as_uint(bc) << 32) | d;   // cost>=0: bit order = numeric
    u64 ok  = __shfl_xor(key, 1);                     // other h half
    return ok < key ? ok : key;                       // valid in lane 0
}

// unpipelined full pass (wave 0's dy=16 only) — verified R2/R6/R8 path
__device__ __forceinline__ u64 sad_pass(const float* Wl, const float S[CC][8],
                                        int dy, int i, int h, int jg) {
    float acc[9];
    #pragma unroll
    for (int a = 0; a < 9; ++a) acc[a] = 0.f;
    #pragma unroll
    for (int c = 0; c < CC; ++c) {
        const int wb = c * (WROWS * WSTR) + (dy + i) * WSTR + 8 * (h + jg);
        f4a w[4] = { *(const f4a*)&Wl[wb + 0], *(const f4a*)&Wl[wb + 4],
                     *(const f4a*)&Wl[wb + 8], *(const f4a*)&Wl[wb + 12] };
        sad_c(w, S[c], acc);
    }
    return reduce_tail(acc, dy, h);
}

__global__ __launch_bounds__(BLK, 4) void tile_kernel(const float* __restrict__ src,
                                                      const float* __restrict__ dst,
                                                      const int* __restrict__ offset,
                                                      float* __restrict__ out) {
    __shared__ float Wl[CC * WROWS * WSTR];   // 13824 B
    __shared__ u64   keyL[4];

    const int bid  = blockIdx.x;
    const int tile = ((bid & 7) << 9) | (bid >> 3);  // XCD-banding swizzle
    const int b  = tile >> 10;
    const int th = (tile >> 5) & 31;
    const int tw = tile & 31;
    const int ti = th * TILE, tj = tw * TILE;
    const int oy = offset[(b * 2 + 0) * 1024 + th * 32 + tw];
    const int ox = offset[(b * 2 + 1) * 1024 + th * 32 + tw];
    const int t  = threadIdx.x;

    // lane map: h=bit0 (dx 0..8 / 8..16), jg=bit1 (j half), i=bits2..5 (row)
    const int wv = t >> 6;
    const int l  = t & 63;
    const int h  = l & 1;
    const int jg = (l >> 1) & 1;
    const int i  = l >> 2;
    const int colb = 8 * (h + jg);

    // ---- stage 3x32x32 dst window (zero-padded) coalesced into LDS ----
    const int gy0 = ti + oy - RR;
    const int gx0 = tj + ox - RR;
    for (int k = t; k < CC * WROWS * 8; k += BLK) {   // 768 float4 chunks, 3 iters
        int c   = k >> 8;
        int rem = k & 255;
        int row = rem >> 3;
        int cc  = (rem & 7) << 2;
        int gy = gy0 + row;
        int gx = gx0 + cc;
        float4 v = make_float4(0.f, 0.f, 0.f, 0.f);
        if ((unsigned)gy < HH) {
            const float* p = dst + ((size_t)(b * CC + c) * HH + gy) * WW;
            if ((unsigned)gx <= WW - 4) {
                f4a u = *(const f4a*)(p + gx);
                v = make_float4(u.x, u.y, u.z, u.w);
            } else {
                float* ve = (float*)&v;
                #pragma unroll
                for (int e = 0; e < 4; ++e) {
                    int g = gx + e;
                    if ((unsigned)g < WW) ve[e] = p[g];
                }
            }
        }
        *(f4a*)&Wl[c * (WROWS * WSTR) + row * WSTR + cc] = *(f4a*)&v;
    }

    // ---- S fragment straight from global into regs (bit-exact, R5/R6/R8) ----
    float S[CC][8];
    {
        const float* sp = src + ((size_t)(b * CC) * HH + ti + i) * WW + tj + 8 * jg;
        #pragma unroll
        for (int c = 0; c < CC; ++c) {
            f4a s0 = *(const f4a*)(sp + (size_t)c * HH * WW);
            f4a s1 = *(const f4a*)(sp + (size_t)c * HH * WW + 4);
            S[c][0]=s0.x; S[c][1]=s0.y; S[c][2]=s0.z; S[c][3]=s0.w;
            S[c][4]=s1.x; S[c][5]=s1.y; S[c][6]=s1.z; S[c][7]=s1.w;
        }
    }
    __syncthreads();

    // ---- software-pipelined pass sequence: 12 (pass,channel) chunks,
    //      double-buffered so chunk k+1's ds_reads fly under chunk k's SAD.
    //      All buffer indices compile-time (full unroll). FP order == R8. ----
    f4a buf[2][4];
    {   // prologue: chunk 0 = (p=0, c=0), dy = wv
        const int wb = (wv + i) * WSTR + colb;
        buf[0][0] = *(const f4a*)&Wl[wb + 0];
        buf[0][1] = *(const f4a*)&Wl[wb + 4];
        buf[0][2] = *(const f4a*)&Wl[wb + 8];
        buf[0][3] = *(const f4a*)&Wl[wb + 12];
    }
    u64 bestkey = ~0ull;
    #pragma unroll
    for (int p = 0; p < 4; ++p) {
        float acc[9];
        #pragma unroll
        for (int a = 0; a < 9; ++a) acc[a] = 0.f;
        #pragma unroll
        for (int c = 0; c < CC; ++c) {
            const int k  = 3 * p + c;
            const int kn = k + 1;
            if (kn < 12) {      // issue next chunk's reads before this SAD
                const int pn = kn / 3, cn = kn % 3;
                const int wb = cn * (WROWS * WSTR) + (wv + 4 * pn + i) * WSTR + colb;
                buf[kn & 1][0] = *(const f4a*)&Wl[wb + 0];
                buf[kn & 1][1] = *(const f4a*)&Wl[wb + 4];
                buf[kn & 1][2] = *(const f4a*)&Wl[wb + 8];
                buf[kn & 1][3] = *(const f4a*)&Wl[wb + 12];
            }
            sad_c(buf[k & 1], S[c], acc);
        }
        u64 k2 = reduce_tail(acc, wv + 4 * p, h);
        if (k2 < bestkey) bestkey = k2;
    }
    if (wv == 0) {              // dy = 16: unpipelined verified path
        u64 k2 = sad_pass(Wl, S, 16, i, h, jg);
        if (k2 < bestkey) bestkey = k2;
    }
    if (l == 0) keyL[wv] = bestkey;
    __syncthreads();

    // block-wide winner (u64 min; d in low bits gives exact smallest-d ties)
    u64 wk = keyL[0];
    #pragma unroll
    for (int w = 1; w < 4; ++w) { u64 kw = keyL[w]; if (kw < wk) wk = kw; }
    const int d   = (int)(wk & 0xFFFFFFFFu);
    const int bdy = d / ND;
    const int bdx = d - bdy * ND;

    if (t == 0) out[(b * 2 + 0) * 1024 + th * 32 + tw] = (float)(oy + bdy - RR);
    if (t == 1) out[(b * 2 + 1) * 1024 + th * 32 + tw] = (float)(ox + bdx - RR);

    // aligned tile is already in the LDS window; dwordx4 coalesced stores
    float* aligned = out + BB * 2 * 1024;
    if (t < 192) {
        const int c   = t >> 6;
        const int rem = t & 63;
        const int ii  = rem >> 2;
        const int jj4 = (rem & 3) << 2;
        const float* wp = &Wl[c * (WROWS * WSTR) + (bdy + ii) * WSTR + bdx + jj4];
        float4 v = make_float4(wp[0], wp[1], wp[2], wp[3]);
        *(f4a*)&aligned[((size_t)(b * CC + c) * HH + ti + ii) * WW + tj + jj4] =
            *(f4a*)&v;
    }
}

extern "C" void kernel_launch(void* const* d_in, const int* in_sizes, int n_in,
                              void* d_out, int out_size, void* d_ws, size_t ws_size,
                              hipStream_t stream) {
    const float* src    = (const float*)d_in[0];
    const float* dst    = (const float*)d_in[1];
    const int*   offset = (const int*)d_in[2];
    float*       out    = (float*)d_out;
    tile_kernel<<<dim3(BB * 1024), BLK, 0, stream>>>(src, dst, offset, out);
}